// Round 11
// baseline (2017.339 us; speedup 1.0000x reference)
//
#include <hip/hip_runtime.h>
#include <math.h>

// Problem constants (4, 19, 512, 512) fp32
#define BB 4
#define CC 19
#define HH 512
#define WW 512
#define NSLICE (BB * CC)        // 76
#define SLICE  (HH * WW)        // 262144
#define W4     (WW / 4)         // 128 float4 per row
#define EPS    1e-12f
#define NEGINF (-INFINITY)

// time-tiling params
#define TSTEPS 16
#define NPASS  16               // 256 / TSTEPS

// Grid (R8, proven): 512 big tiles (64-out/96-in) + 192 small (32-out/64-in)
// = 704 blocks, big-first -> 2 full block-waves of bigs + 1 partial of smalls.
#define NBIG   512
#define NSMALL 192

// PROVEN FACTS (R0-R10):
//  * Register budget: T threads -> ceil(T/64/4) waves/EU -> 512/that total
//    regs (half arch-VGPR half AGPR). 512thr = 256 total; the 192-float c+x
//    state allocates CLEAN only with the rolling hA/hB/hC body. Deviations
//    spilled (R1-R4, R6 deferred-commit) or thrashed L2 (R5/R9 x-stream).
//  * Full persistence impossible (c+x 160MB > 128MB RF); 1 block/CU and
//    2 waves/SIMD structural; no inter-block overlap on a CU.
//  * TSTEPS=16 optimal (8: fixed+load costs x2 across 32 passes; 32: 2x
//    VALU redundancy). Tile-mix makespan floor 256 in-row-units (per-slice
//    integrality); we're at it.
//  * DPP wave_shr/shl:1 halo exchange, old=-inf pad (R7). One barrier/step
//    via double-buffered snapshot (R7). XCD-chunked swizzle (R7).
//  * Init fused into pass 1 (R10: -60us).
//  * R11: snapshot/halo LDS goes float4/b128 (R5/R9-proven layout,
//    SQ_LDS_BANK_CONFLICT=0): 32 scalar DS ops/thread-step -> 8.
//    r-loop body untouched (R6 lesson).
#define TX   64
#define TY   8
#define COLS 8
#define THREADS 512

struct F8 { float4 a, b; };

// DPP lane shifts (gfx9-family wave_shr:1 / wave_shl:1, valid on gfx950).
// bound_ctrl=false keeps `old` in the edge lane -> -inf image pad for free.
__device__ __forceinline__ float dpp_up(float src) {   // lane i <- lane i-1; lane0 -> -inf
    int o = __builtin_amdgcn_update_dpp(__float_as_int(NEGINF), __float_as_int(src),
                                        0x138 /*wave_shr:1*/, 0xF, 0xF, false);
    return __int_as_float(o);
}
__device__ __forceinline__ float dpp_dn(float src) {   // lane i <- lane i+1; lane63 -> -inf
    int o = __builtin_amdgcn_update_dpp(__float_as_int(NEGINF), __float_as_int(src),
                                        0x130 /*wave_shl:1*/, 0xF, 0xF, false);
    return __int_as_float(o);
}

// map blockIdx -> (slice, tile row0) with XCD-chunked bijective swizzle
__device__ __forceinline__ void tile_map(int bid, int& bc, int& tr0, bool& big) {
    if (bid < NBIG) {
        big = true;
        const int g = (bid & 7) * (NBIG / 8) + (bid >> 3);
        if (g < 28 * 8) {                // slices 0..27: 8 big tiles each
            bc  = g >> 3;
            tr0 = (g & 7) << 6;
        } else {                         // slices 28..75: 6 big tiles each
            int g2 = g - 28 * 8;
            bc  = 28 + g2 / 6;
            tr0 = (g2 % 6) << 6;
        }
    } else {
        big = false;                     // rows [384,512) of slices 28..75
        const int sb = bid - NBIG;
        const int h  = (sb & 7) * (NSMALL / 8) + (sb >> 3);
        bc  = 28 + (h >> 2);
        tr0 = 384 + ((h & 3) << 5);
    }
}

// ---------------------------------------------------------------------------
// one tile = TSTEPS fused (maxpool3x3 * x) steps on a 512 x (8R) tile.
// R = rows/thread (compile-time), RR = valid output rows = 8R - 32.
// FIRST: derive c0 = border-masked(-x) from the x load (init fusion).
// LDS: float4 snapshot, 16B lane stride -> ds_*_b128, conflict-free
// (2-way aliasing is free on wave64); 64 KiB total.
template<int R, int RR, bool FIRST>
__device__ __forceinline__ void pass_body(const float* __restrict__ in,
                                          const float* __restrict__ xg,
                                          float* __restrict__ out,
                                          int bc, int tr0,
                                          float4 (&Tb)[2][TY][2][64],
                                          float4 (&Bb)[2][TY][2][64]) {
    const int tid  = threadIdx.x;
    const int tx   = tid & 63;          // lane = column group
    const int ty   = tid >> 6;          // wave = thread-row
    const int gstart = tr0 - TSTEPS;    // tile row a=0 -> global row
    const int row0   = gstart + ty * R; // this thread's r=0 global row
    const int col0   = tx * COLS;
    const size_t sbase = (size_t)bc * SLICE;

    const float4 neg4 = make_float4(NEGINF, NEGINF, NEGINF, NEGINF);
    const float4 one4 = make_float4(1.f, 1.f, 1.f, 1.f);

    float4 cl[R], cr[R], xl[R], xr_[R];

#pragma unroll
    for (int r = 0; r < R; ++r) {
        int grow = row0 + r;
        if (grow >= 0 && grow < HH) {               // wave-uniform branch
            const float4* q = (const float4*)(xg + sbase + (size_t)grow * WW + col0);
            xl[r] = q[0]; xr_[r] = q[1];
            if (FIRST) {
                // c0 = -x, with borders (row 0/511 all cols; col 0/511) = 1
                float4 ca, cb;
                ca.x = -xl[r].x;  ca.y = -xl[r].y;  ca.z = -xl[r].z;  ca.w = -xl[r].w;
                cb.x = -xr_[r].x; cb.y = -xr_[r].y; cb.z = -xr_[r].z; cb.w = -xr_[r].w;
                if (grow == 0 || grow == HH - 1) {  // wave-uniform
                    ca = one4; cb = one4;
                } else {
                    if (tx == 0)  ca.x = 1.0f;      // image left col
                    if (tx == 63) cb.w = 1.0f;      // image right col
                }
                cl[r] = ca; cr[r] = cb;
            } else {
                const float4* p = (const float4*)(in + sbase + (size_t)grow * WW + col0);
                cl[r] = p[0]; cr[r] = p[1];
            }
        } else {
            cl[r] = neg4; cr[r] = neg4; xl[r] = one4; xr_[r] = one4;
        }
    }

    // horizontal 3-max of one 8-px row (a=cols0-3, b=cols4-7), DPP exchange
    auto hrow = [&](float4 a, float4 b) -> F8 {
        float lpx = dpp_up(b.w);       // left neighbor's col7; lane0 = -inf pad
        float rpx = dpp_dn(a.x);       // right neighbor's col0; lane63 = -inf pad
        F8 h;
        h.a.x = fmaxf(fmaxf(lpx, a.x), a.y);
        h.a.y = fmaxf(fmaxf(a.x, a.y), a.z);
        h.a.z = fmaxf(fmaxf(a.y, a.z), a.w);
        h.a.w = fmaxf(fmaxf(a.z, a.w), b.x);
        h.b.x = fmaxf(fmaxf(a.w, b.x), b.y);
        h.b.y = fmaxf(fmaxf(b.x, b.y), b.z);
        h.b.z = fmaxf(fmaxf(b.y, b.z), b.w);
        h.b.w = fmaxf(fmaxf(b.z, b.w), rpx);
        return h;
    };

    for (int t = 0; t < TSTEPS; ++t) {
        const int buf = t & 1;
        // snapshot pre-step top/bottom rows (ds_write_b128 x4)
        Tb[buf][ty][0][tx] = cl[0];
        Tb[buf][ty][1][tx] = cr[0];
        Bb[buf][ty][0][tx] = cl[R - 1];
        Bb[buf][ty][1][tx] = cr[R - 1];
        __syncthreads();

        float4 upA, upB, dnA, dnB;
        if (ty > 0) {                    // wave-uniform (ds_read_b128 x2)
            upA = Bb[buf][ty - 1][0][tx];
            upB = Bb[buf][ty - 1][1][tx];
        } else { upA = neg4; upB = neg4; }
        if (ty < TY - 1) {
            dnA = Tb[buf][ty + 1][0][tx];
            dnB = Tb[buf][ty + 1][1][tx];
        } else { dnA = neg4; dnB = neg4; }

        F8 hA = hrow(upA, upB);          // row r-1 (neighbor)
        F8 hB = hrow(cl[0], cr[0]);      // row r
#pragma unroll
        for (int r = 0; r < R; ++r) {
            F8 hC;
            if (r + 1 < R) hC = hrow(cl[r + 1], cr[r + 1]);
            else           hC = hrow(dnA, dnB);
            float4 vl, vr;
            vl.x = fmaxf(fmaxf(hA.a.x, hB.a.x), hC.a.x);
            vl.y = fmaxf(fmaxf(hA.a.y, hB.a.y), hC.a.y);
            vl.z = fmaxf(fmaxf(hA.a.z, hB.a.z), hC.a.z);
            vl.w = fmaxf(fmaxf(hA.a.w, hB.a.w), hC.a.w);
            vr.x = fmaxf(fmaxf(hA.b.x, hB.b.x), hC.b.x);
            vr.y = fmaxf(fmaxf(hA.b.y, hB.b.y), hC.b.y);
            vr.z = fmaxf(fmaxf(hA.b.z, hB.b.z), hC.b.z);
            vr.w = fmaxf(fmaxf(hA.b.w, hB.b.w), hC.b.w);
            cl[r].x = vl.x * xl[r].x;  cl[r].y = vl.y * xl[r].y;
            cl[r].z = vl.z * xl[r].z;  cl[r].w = vl.w * xl[r].w;
            cr[r].x = vr.x * xr_[r].x; cr[r].y = vr.y * xr_[r].y;
            cr[r].z = vr.z * xr_[r].z; cr[r].w = vr.w * xr_[r].w;
            hA = hB; hB = hC;
        }
        // rows outside the image must be -inf before the next step's reads
#pragma unroll
        for (int r = 0; r < R; ++r) {
            int grow = row0 + r;
            if (grow < 0 || grow >= HH) { cl[r] = neg4; cr[r] = neg4; }  // uniform
        }
        // no trailing barrier: next step writes the OTHER buffer; this
        // buffer is rewritten only at step t+2, after barrier t+1.
    }

    // store valid center rows: tile rows a in [TSTEPS, TSTEPS+RR)
#pragma unroll
    for (int r = 0; r < R; ++r) {
        int a = ty * R + r;              // wave-uniform condition
        if (a >= TSTEPS && a < TSTEPS + RR) {
            int grow = row0 + r;
            float4* p = (float4*)(out + sbase + (size_t)grow * WW + col0);
            p[0] = cl[r]; p[1] = cr[r];
        }
    }
}

// ---------------------------------------------------------------------------
// steady pass (passes 2..16): reads ping-pong buffer.
__global__ __launch_bounds__(THREADS, 1)
void pass_kernel(const float* __restrict__ in, const float* __restrict__ xg,
                 float* __restrict__ out) {
    __shared__ float4 Tb[2][TY][2][64];   // dbuf float4 snapshot; 64 KiB total
    __shared__ float4 Bb[2][TY][2][64];
    int bc, tr0; bool big;
    tile_map(blockIdx.x, bc, tr0, big);
    if (big) pass_body<12, 64, false>(in, xg, out, bc, tr0, Tb, Bb);
    else     pass_body<8, 32, false>(in, xg, out, bc, tr0, Tb, Bb);
}

// first pass: c0 derived from x inline (init fusion). Separate __global__
// so the steady kernel's register allocation is untouched.
__global__ __launch_bounds__(THREADS, 1)
void pass_first_kernel(const float* __restrict__ xg, float* __restrict__ out) {
    __shared__ float4 Tb[2][TY][2][64];
    __shared__ float4 Bb[2][TY][2][64];
    int bc, tr0; bool big;
    tile_map(blockIdx.x, bc, tr0, big);
    if (big) pass_body<12, 64, true>(nullptr, xg, out, bc, tr0, Tb, Bb);
    else     pass_body<8, 32, true>(nullptr, xg, out, bc, tr0, Tb, Bb);
}

// ---------------------------------------------------------------------------
// final: norm over channel dim (19), out = cur * x / max(||cur||_2, eps)
__global__ void norm_kernel(const float* __restrict__ cur,
                            const float* __restrict__ x,
                            float* __restrict__ out) {
    int t = blockIdx.x * blockDim.x + threadIdx.x;
    int j4 = t & (W4 - 1);
    int i  = (t >> 7) & (HH - 1);
    int b  = t >> 16;
    size_t off = (size_t)b * CC * SLICE + (size_t)i * WW + (j4 << 2);

    float4 vals[CC];
    float sx = 0.f, sy = 0.f, sz = 0.f, sw = 0.f;
#pragma unroll
    for (int c = 0; c < CC; ++c) {
        float4 v = *(const float4*)(cur + off + (size_t)c * SLICE);
        vals[c] = v;
        sx += v.x * v.x; sy += v.y * v.y; sz += v.z * v.z; sw += v.w * v.w;
    }
    float4 r;
    r.x = 1.0f / fmaxf(sqrtf(sx), EPS);
    r.y = 1.0f / fmaxf(sqrtf(sy), EPS);
    r.z = 1.0f / fmaxf(sqrtf(sz), EPS);
    r.w = 1.0f / fmaxf(sqrtf(sw), EPS);
#pragma unroll
    for (int c = 0; c < CC; ++c) {
        float4 xv = *(const float4*)(x + off + (size_t)c * SLICE);
        float4 o;
        o.x = vals[c].x * xv.x * r.x;
        o.y = vals[c].y * xv.y * r.y;
        o.z = vals[c].z * xv.z * r.z;
        o.w = vals[c].w * xv.w * r.w;
        *(float4*)(out + off + (size_t)c * SLICE) = o;
    }
}

// ---------------------------------------------------------------------------
extern "C" void kernel_launch(void* const* d_in, const int* in_sizes, int n_in,
                              void* d_out, int out_size, void* d_ws, size_t ws_size,
                              hipStream_t stream) {
    const float* x = (const float*)d_in[0];
    float* out = (float*)d_out;
    float* ws  = (float*)d_ws;        // >= 79,691,776 B

    const int passBlocks = NBIG + NSMALL;            // 704
    const int normBlocks = BB * HH * W4 / 256;       // 1024

    // pass 1 (init fused): x -> out.  passes 2..16 ping-pong; result in ws.
    pass_first_kernel<<<passBlocks, THREADS, 0, stream>>>(x, out);
    float* a = out;
    float* b = ws;
    for (int it = 1; it < NPASS; ++it) {
        pass_kernel<<<passBlocks, THREADS, 0, stream>>>(a, x, b);
        float* tmp = a; a = b; b = tmp;
    }
    // result in ws
    norm_kernel<<<normBlocks, 256, 0, stream>>>(ws, x, out);
}

// Round 12
// 1937.484 us; speedup vs baseline: 1.0412x; 1.0412x over previous
//
#include <hip/hip_runtime.h>
#include <math.h>

// Problem constants (4, 19, 512, 512) fp32
#define BB 4
#define CC 19
#define HH 512
#define WW 512
#define NSLICE (BB * CC)        // 76
#define SLICE  (HH * WW)        // 262144
#define W4     (WW / 4)         // 128 float4 per row
#define EPS    1e-12f
#define NEGINF (-INFINITY)

// time-tiling params
#define TSTEPS 16
#define NPASS  16               // 256 / TSTEPS

// Grid (R8, proven): 512 big tiles (64-out/96-in) + 192 small (32-out/64-in)
// = 704 blocks, big-first -> 2 full block-waves of bigs + 1 partial of smalls.
#define NBIG   512
#define NSMALL 192

// PROVEN FACTS (R0-R11):
//  * Register budget: T threads -> ceil(T/64/4) waves/EU -> 512/that total
//    regs (half arch-VGPR half AGPR). 512thr = 256 total; the 192-float c+x
//    state allocates CLEAN only with the rolling hA/hB/hC body. Deviations
//    spilled (R1-R4, R6 deferred-commit) or thrashed L2 (R5/R9 x-stream).
//  * Full persistence impossible (c+x 160MB > 128MB RF); 1 block/CU and
//    2 waves/SIMD structural.
//  * DPP wave_shr/shl:1 halo exchange, old=-inf pad (R7: -23us/pass).
//    One barrier/step via dbuf snapshot (R7). XCD-chunked swizzle (R7).
//    Init fused into pass 1 (R10: -60us). b128 snapshot (R11: neutral --
//    DS op count was not on the critical path).
//  * R12: VALU issue per block-slot = 20.7us vs 8.3us pure-math floor ->
//    ~half the VALU is per-step overhead (buf-dependent LDS addressing,
//    loop bookkeeping). #pragma unroll 2 on the t-loop statically resolves
//    buf=0/1 -> LDS addresses become constant sets; r-loop body untouched.
#define TX   64
#define TY   8
#define COLS 8
#define THREADS 512

struct F8 { float4 a, b; };

// DPP lane shifts (gfx9-family wave_shr:1 / wave_shl:1, valid on gfx950).
// bound_ctrl=false keeps `old` in the edge lane -> -inf image pad for free.
__device__ __forceinline__ float dpp_up(float src) {   // lane i <- lane i-1; lane0 -> -inf
    int o = __builtin_amdgcn_update_dpp(__float_as_int(NEGINF), __float_as_int(src),
                                        0x138 /*wave_shr:1*/, 0xF, 0xF, false);
    return __int_as_float(o);
}
__device__ __forceinline__ float dpp_dn(float src) {   // lane i <- lane i+1; lane63 -> -inf
    int o = __builtin_amdgcn_update_dpp(__float_as_int(NEGINF), __float_as_int(src),
                                        0x130 /*wave_shl:1*/, 0xF, 0xF, false);
    return __int_as_float(o);
}

// map blockIdx -> (slice, tile row0) with XCD-chunked bijective swizzle
__device__ __forceinline__ void tile_map(int bid, int& bc, int& tr0, bool& big) {
    if (bid < NBIG) {
        big = true;
        const int g = (bid & 7) * (NBIG / 8) + (bid >> 3);
        if (g < 28 * 8) {                // slices 0..27: 8 big tiles each
            bc  = g >> 3;
            tr0 = (g & 7) << 6;
        } else {                         // slices 28..75: 6 big tiles each
            int g2 = g - 28 * 8;
            bc  = 28 + g2 / 6;
            tr0 = (g2 % 6) << 6;
        }
    } else {
        big = false;                     // rows [384,512) of slices 28..75
        const int sb = bid - NBIG;
        const int h  = (sb & 7) * (NSMALL / 8) + (sb >> 3);
        bc  = 28 + (h >> 2);
        tr0 = 384 + ((h & 3) << 5);
    }
}

// ---------------------------------------------------------------------------
// one tile = TSTEPS fused (maxpool3x3 * x) steps on a 512 x (8R) tile.
// R = rows/thread (compile-time), RR = valid output rows = 8R - 32.
// FIRST: derive c0 = border-masked(-x) from the x load (init fusion).
// LDS: float4 snapshot, 16B lane stride -> ds_*_b128, conflict-free; 64 KiB.
template<int R, int RR, bool FIRST>
__device__ __forceinline__ void pass_body(const float* __restrict__ in,
                                          const float* __restrict__ xg,
                                          float* __restrict__ out,
                                          int bc, int tr0,
                                          float4 (&Tb)[2][TY][2][64],
                                          float4 (&Bb)[2][TY][2][64]) {
    const int tid  = threadIdx.x;
    const int tx   = tid & 63;          // lane = column group
    const int ty   = tid >> 6;          // wave = thread-row
    const int gstart = tr0 - TSTEPS;    // tile row a=0 -> global row
    const int row0   = gstart + ty * R; // this thread's r=0 global row
    const int col0   = tx * COLS;
    const size_t sbase = (size_t)bc * SLICE;

    const float4 neg4 = make_float4(NEGINF, NEGINF, NEGINF, NEGINF);
    const float4 one4 = make_float4(1.f, 1.f, 1.f, 1.f);

    float4 cl[R], cr[R], xl[R], xr_[R];

#pragma unroll
    for (int r = 0; r < R; ++r) {
        int grow = row0 + r;
        if (grow >= 0 && grow < HH) {               // wave-uniform branch
            const float4* q = (const float4*)(xg + sbase + (size_t)grow * WW + col0);
            xl[r] = q[0]; xr_[r] = q[1];
            if (FIRST) {
                // c0 = -x, with borders (row 0/511 all cols; col 0/511) = 1
                float4 ca, cb;
                ca.x = -xl[r].x;  ca.y = -xl[r].y;  ca.z = -xl[r].z;  ca.w = -xl[r].w;
                cb.x = -xr_[r].x; cb.y = -xr_[r].y; cb.z = -xr_[r].z; cb.w = -xr_[r].w;
                if (grow == 0 || grow == HH - 1) {  // wave-uniform
                    ca = one4; cb = one4;
                } else {
                    if (tx == 0)  ca.x = 1.0f;      // image left col
                    if (tx == 63) cb.w = 1.0f;      // image right col
                }
                cl[r] = ca; cr[r] = cb;
            } else {
                const float4* p = (const float4*)(in + sbase + (size_t)grow * WW + col0);
                cl[r] = p[0]; cr[r] = p[1];
            }
        } else {
            cl[r] = neg4; cr[r] = neg4; xl[r] = one4; xr_[r] = one4;
        }
    }

    // horizontal 3-max of one 8-px row (a=cols0-3, b=cols4-7), DPP exchange
    auto hrow = [&](float4 a, float4 b) -> F8 {
        float lpx = dpp_up(b.w);       // left neighbor's col7; lane0 = -inf pad
        float rpx = dpp_dn(a.x);       // right neighbor's col0; lane63 = -inf pad
        F8 h;
        h.a.x = fmaxf(fmaxf(lpx, a.x), a.y);
        h.a.y = fmaxf(fmaxf(a.x, a.y), a.z);
        h.a.z = fmaxf(fmaxf(a.y, a.z), a.w);
        h.a.w = fmaxf(fmaxf(a.z, a.w), b.x);
        h.b.x = fmaxf(fmaxf(a.w, b.x), b.y);
        h.b.y = fmaxf(fmaxf(b.x, b.y), b.z);
        h.b.z = fmaxf(fmaxf(b.y, b.z), b.w);
        h.b.w = fmaxf(fmaxf(b.z, b.w), rpx);
        return h;
    };

    // unroll 2: buf statically 0/1 -> LDS addresses become two constant
    // sets (hoisted/immediate); halves loop bookkeeping. Body unchanged.
#pragma unroll 2
    for (int t = 0; t < TSTEPS; ++t) {
        const int buf = t & 1;
        // snapshot pre-step top/bottom rows (ds_write_b128 x4)
        Tb[buf][ty][0][tx] = cl[0];
        Tb[buf][ty][1][tx] = cr[0];
        Bb[buf][ty][0][tx] = cl[R - 1];
        Bb[buf][ty][1][tx] = cr[R - 1];
        __syncthreads();

        float4 upA, upB, dnA, dnB;
        if (ty > 0) {                    // wave-uniform (ds_read_b128 x2)
            upA = Bb[buf][ty - 1][0][tx];
            upB = Bb[buf][ty - 1][1][tx];
        } else { upA = neg4; upB = neg4; }
        if (ty < TY - 1) {
            dnA = Tb[buf][ty + 1][0][tx];
            dnB = Tb[buf][ty + 1][1][tx];
        } else { dnA = neg4; dnB = neg4; }

        F8 hA = hrow(upA, upB);          // row r-1 (neighbor)
        F8 hB = hrow(cl[0], cr[0]);      // row r
#pragma unroll
        for (int r = 0; r < R; ++r) {
            F8 hC;
            if (r + 1 < R) hC = hrow(cl[r + 1], cr[r + 1]);
            else           hC = hrow(dnA, dnB);
            float4 vl, vr;
            vl.x = fmaxf(fmaxf(hA.a.x, hB.a.x), hC.a.x);
            vl.y = fmaxf(fmaxf(hA.a.y, hB.a.y), hC.a.y);
            vl.z = fmaxf(fmaxf(hA.a.z, hB.a.z), hC.a.z);
            vl.w = fmaxf(fmaxf(hA.a.w, hB.a.w), hC.a.w);
            vr.x = fmaxf(fmaxf(hA.b.x, hB.b.x), hC.b.x);
            vr.y = fmaxf(fmaxf(hA.b.y, hB.b.y), hC.b.y);
            vr.z = fmaxf(fmaxf(hA.b.z, hB.b.z), hC.b.z);
            vr.w = fmaxf(fmaxf(hA.b.w, hB.b.w), hC.b.w);
            cl[r].x = vl.x * xl[r].x;  cl[r].y = vl.y * xl[r].y;
            cl[r].z = vl.z * xl[r].z;  cl[r].w = vl.w * xl[r].w;
            cr[r].x = vr.x * xr_[r].x; cr[r].y = vr.y * xr_[r].y;
            cr[r].z = vr.z * xr_[r].z; cr[r].w = vr.w * xr_[r].w;
            hA = hB; hB = hC;
        }
        // rows outside the image must be -inf before the next step's reads
#pragma unroll
        for (int r = 0; r < R; ++r) {
            int grow = row0 + r;
            if (grow < 0 || grow >= HH) { cl[r] = neg4; cr[r] = neg4; }  // uniform
        }
        // no trailing barrier: next step writes the OTHER buffer; this
        // buffer is rewritten only at step t+2, after barrier t+1.
    }

    // store valid center rows: tile rows a in [TSTEPS, TSTEPS+RR)
#pragma unroll
    for (int r = 0; r < R; ++r) {
        int a = ty * R + r;              // wave-uniform condition
        if (a >= TSTEPS && a < TSTEPS + RR) {
            int grow = row0 + r;
            float4* p = (float4*)(out + sbase + (size_t)grow * WW + col0);
            p[0] = cl[r]; p[1] = cr[r];
        }
    }
}

// ---------------------------------------------------------------------------
// steady pass (passes 2..16): reads ping-pong buffer.
__global__ __launch_bounds__(THREADS, 1)
void pass_kernel(const float* __restrict__ in, const float* __restrict__ xg,
                 float* __restrict__ out) {
    __shared__ float4 Tb[2][TY][2][64];   // dbuf float4 snapshot; 64 KiB total
    __shared__ float4 Bb[2][TY][2][64];
    int bc, tr0; bool big;
    tile_map(blockIdx.x, bc, tr0, big);
    if (big) pass_body<12, 64, false>(in, xg, out, bc, tr0, Tb, Bb);
    else     pass_body<8, 32, false>(in, xg, out, bc, tr0, Tb, Bb);
}

// first pass: c0 derived from x inline (init fusion). Separate __global__
// so the steady kernel's register allocation is untouched.
__global__ __launch_bounds__(THREADS, 1)
void pass_first_kernel(const float* __restrict__ xg, float* __restrict__ out) {
    __shared__ float4 Tb[2][TY][2][64];
    __shared__ float4 Bb[2][TY][2][64];
    int bc, tr0; bool big;
    tile_map(blockIdx.x, bc, tr0, big);
    if (big) pass_body<12, 64, true>(nullptr, xg, out, bc, tr0, Tb, Bb);
    else     pass_body<8, 32, true>(nullptr, xg, out, bc, tr0, Tb, Bb);
}

// ---------------------------------------------------------------------------
// final: norm over channel dim (19), out = cur * x / max(||cur||_2, eps)
__global__ void norm_kernel(const float* __restrict__ cur,
                            const float* __restrict__ x,
                            float* __restrict__ out) {
    int t = blockIdx.x * blockDim.x + threadIdx.x;
    int j4 = t & (W4 - 1);
    int i  = (t >> 7) & (HH - 1);
    int b  = t >> 16;
    size_t off = (size_t)b * CC * SLICE + (size_t)i * WW + (j4 << 2);

    float4 vals[CC];
    float sx = 0.f, sy = 0.f, sz = 0.f, sw = 0.f;
#pragma unroll
    for (int c = 0; c < CC; ++c) {
        float4 v = *(const float4*)(cur + off + (size_t)c * SLICE);
        vals[c] = v;
        sx += v.x * v.x; sy += v.y * v.y; sz += v.z * v.z; sw += v.w * v.w;
    }
    float4 r;
    r.x = 1.0f / fmaxf(sqrtf(sx), EPS);
    r.y = 1.0f / fmaxf(sqrtf(sy), EPS);
    r.z = 1.0f / fmaxf(sqrtf(sz), EPS);
    r.w = 1.0f / fmaxf(sqrtf(sw), EPS);
#pragma unroll
    for (int c = 0; c < CC; ++c) {
        float4 xv = *(const float4*)(x + off + (size_t)c * SLICE);
        float4 o;
        o.x = vals[c].x * xv.x * r.x;
        o.y = vals[c].y * xv.y * r.y;
        o.z = vals[c].z * xv.z * r.z;
        o.w = vals[c].w * xv.w * r.w;
        *(float4*)(out + off + (size_t)c * SLICE) = o;
    }
}

// ---------------------------------------------------------------------------
extern "C" void kernel_launch(void* const* d_in, const int* in_sizes, int n_in,
                              void* d_out, int out_size, void* d_ws, size_t ws_size,
                              hipStream_t stream) {
    const float* x = (const float*)d_in[0];
    float* out = (float*)d_out;
    float* ws  = (float*)d_ws;        // >= 79,691,776 B

    const int passBlocks = NBIG + NSMALL;            // 704
    const int normBlocks = BB * HH * W4 / 256;       // 1024

    // pass 1 (init fused): x -> out.  passes 2..16 ping-pong; result in ws.
    pass_first_kernel<<<passBlocks, THREADS, 0, stream>>>(x, out);
    float* a = out;
    float* b = ws;
    for (int it = 1; it < NPASS; ++it) {
        pass_kernel<<<passBlocks, THREADS, 0, stream>>>(a, x, b);
        float* tmp = a; a = b; b = tmp;
    }
    // result in ws
    norm_kernel<<<normBlocks, 256, 0, stream>>>(ws, x, out);
}